// Round 4
// baseline (688.560 us; speedup 1.0000x reference)
//
#include <hip/hip_runtime.h>

#define BIGF 3.402823466e38f
#define LCAP 2048u
#define NB   2048
#define NT   256

typedef float f32x4 __attribute__((ext_vector_type(4)));

// ---------------------------------------------------------------------------
// State in workspace. Poisoned 0xAA each timed call; k0 inits countA (needed
// by k1); k1r inits everything else (it runs between k1 and all consumers).
// ---------------------------------------------------------------------------
struct State {
  double sum0, sumsq0;
  double sum1, sumsq1;
  double sum2, sumsq2;
  unsigned n0, n1, n2;
  float maxabs0, minnz0, maxnz0;
  float maxabs1, minnz1, maxnz1;
  float maxabs2, minnz2, maxnz2;
  float bmin0, bmax0;     // iter-0 inlier min/max
  float bmin1, bmax1;     // iter-1 band min/max
  unsigned countA;        // speculative superset records in bufA (written by k1)
  unsigned count1;        // |x| > thr0 records in bufB
  unsigned count2;        // |x| > thr1 records in buf2
  float thr0f;
  int special0;           // thr0 > maxabs0
  int fallback;           // speculation failed -> k2_full path
  float thr[10], delta[10], zp[10];
  int valid[10];
};

// ---------------------------------------------------------------------------
__device__ inline void atomicMinF(float* addr, float v) {
  unsigned* ua = (unsigned*)addr;
  unsigned cur = *ua;
  while (v < __uint_as_float(cur)) {
    unsigned prev = atomicCAS(ua, cur, __float_as_uint(v));
    if (prev == cur) break;
    cur = prev;
  }
}
__device__ inline void atomicMaxF(float* addr, float v) {
  unsigned* ua = (unsigned*)addr;
  unsigned cur = *ua;
  while (v > __uint_as_float(cur)) {
    unsigned prev = atomicCAS(ua, cur, __float_as_uint(v));
    if (prev == cur) break;
    cur = prev;
  }
}

// ---------------------------------------------------------------------------
struct Acc8 {
  double sum, sumsq;
  unsigned cnt;
  float maxabs, minnz, maxnz, bmin, bmax;
};
struct AccP { Acc8 a; float tspec; };

__device__ inline void acc_init(Acc8& a) {
  a.sum = 0.0; a.sumsq = 0.0; a.cnt = 0u;
  a.maxabs = 0.0f;
  a.minnz = BIGF; a.maxnz = -BIGF;
  a.bmin = BIGF; a.bmax = -BIGF;
}
__device__ inline void acc_merge(Acc8& a, const Acc8& b) {
  a.sum += b.sum; a.sumsq += b.sumsq; a.cnt += b.cnt;
  a.maxabs = fmaxf(a.maxabs, b.maxabs);
  a.minnz = fminf(a.minnz, b.minnz); a.maxnz = fmaxf(a.maxnz, b.maxnz);
  a.bmin = fminf(a.bmin, b.bmin);   a.bmax = fmaxf(a.bmax, b.bmax);
}
__device__ inline void acc_wave_reduce(Acc8& a) {
  #pragma unroll
  for (int off = 32; off > 0; off >>= 1) {
    a.sum    += __shfl_down(a.sum, off);
    a.sumsq  += __shfl_down(a.sumsq, off);
    a.cnt    += __shfl_down(a.cnt, off);
    a.maxabs = fmaxf(a.maxabs, __shfl_down(a.maxabs, off));
    a.minnz  = fminf(a.minnz,  __shfl_down(a.minnz, off));
    a.maxnz  = fmaxf(a.maxnz,  __shfl_down(a.maxnz, off));
    a.bmin   = fminf(a.bmin,   __shfl_down(a.bmin, off));
    a.bmax   = fmaxf(a.bmax,   __shfl_down(a.bmax, off));
  }
}
template <int NWAVES>
__device__ inline bool acc_block_reduce(Acc8& a, Acc8* s_part) {
  __syncthreads();
  acc_wave_reduce(a);
  int tid = threadIdx.x;
  if ((tid & 63) == 0) s_part[tid >> 6] = a;
  __syncthreads();
  if (tid == 0) {
    #pragma unroll
    for (int w = 1; w < NWAVES; ++w) acc_merge(a, s_part[w]);
    return true;
  }
  return false;
}

__device__ inline float compute_thr(double sum, double sumsq, unsigned n) {
  double nf = (double)(n > 0u ? n : 1u);
  double mean = sum / nf;
  double nm1 = nf - 1.0; if (nm1 < 1.0) nm1 = 1.0;
  double var = (sumsq - sum * sum / nf) / nm1;
  if (var < 0.0) var = 0.0;
  return (float)(mean + 3.0 * sqrt(var));
}

__device__ inline void finalize_group(float thr, float maxabs, unsigned n,
                                      float minnz, float maxnz, float bmin, float bmax,
                                      bool clampZero, float* dOut, float* zOut, int* vOut) {
  float xmin, xmax;
  if (thr > maxabs) { xmin = minnz; xmax = maxnz; }
  else {
    xmin = bmin; xmax = bmax;
    if (clampZero) { xmin = fminf(xmin, 0.0f); xmax = fmaxf(xmax, 0.0f); }
  }
  float d = (xmax - xmin) / 255.0f;
  int v = (n > 0u) ? 1 : 0;
  float z;
  if (v && d > 0.0f && d < BIGF) { z = rintf((-xmin) / d); }
  else { d = 1.0f; z = 0.0f; }
  *dOut = d; *zOut = z; *vOut = v;
}

// ---------------------------------------------------------------------------
// K0: only countA must exist before k1.
// ---------------------------------------------------------------------------
__global__ void k0_init(State* st) {
  if (threadIdx.x == 0 && blockIdx.x == 0) st->countA = 0u;
}

// ---------------------------------------------------------------------------
// K1: ONE full pass producing (a) iter-0 stats over nonzero, (b) speculative
// inlier min/max w.r.t. per-block tspec, (c) compacted superset {|x|>tspec}.
// tspec = 0.8*(mean+3sigma) estimated from the block's own first 8192 elems
// (>=30 sigma of sampling noise below true thr0; exact verification in k1r).
// ---------------------------------------------------------------------------
__device__ inline void proc1(float f, float tspec, Acc8& a,
                             unsigned* l_cnt, float* l_buf,
                             State* st, float* __restrict__ bufA, unsigned capA) {
  float ab = fabsf(f);
  bool nz = (f != 0.0f);
  a.cnt += nz ? 1u : 0u;
  double dab = (double)ab;
  a.sum += dab; a.sumsq += dab * dab;
  a.maxabs = fmaxf(a.maxabs, ab);
  a.minnz = fminf(a.minnz, nz ? f : BIGF);
  a.maxnz = fmaxf(a.maxnz, nz ? f : -BIGF);
  bool out = ab > tspec;                       // superset of {|x| > thr0}
  a.bmin = fminf(a.bmin, out ? BIGF : f);      // spec-inliers (zeros included)
  a.bmax = fmaxf(a.bmax, out ? -BIGF : f);
  unsigned long long m = __ballot(out);
  if (m) {
    unsigned lo = (unsigned)m, hi = (unsigned)(m >> 32);
    int pw = (int)__builtin_amdgcn_mbcnt_hi(hi, __builtin_amdgcn_mbcnt_lo(lo, 0u));
    int nout = __builtin_popcountll(m);
    int leader = __builtin_ctzll(m);
    unsigned bbase = 0u;
    if ((int)(threadIdx.x & 63) == leader) bbase = atomicAdd(l_cnt, (unsigned)nout);
    bbase = (unsigned)__shfl((int)bbase, leader);
    if (out) {
      unsigned p = bbase + (unsigned)pw;
      if (p < LCAP) l_buf[p] = f;
      else { unsigned g = atomicAdd(&st->countA, 1u); if (g < capA) bufA[g] = f; }
    }
  }
}

__global__ void __launch_bounds__(256) k1_stats(const float* __restrict__ x, long long n,
                                                AccP* __restrict__ part,
                                                float* __restrict__ bufA, unsigned capA,
                                                State* st) {
  __shared__ Acc8 s_part[4];
  __shared__ float l_buf[LCAP];
  __shared__ unsigned l_cnt, l_base, l_m;
  __shared__ float s_s[4], s_ss[4], s_c[4], s_tspec;
  int tid = threadIdx.x;
  if (tid == 0) l_cnt = 0u;

  const f32x4* x4 = (const f32x4*)x;
  long long n4 = n >> 2;
  long long gtid = (long long)blockIdx.x * NT + tid;
  long long nthreads = (long long)gridDim.x * NT;
  long long step = nthreads * 8;
  long long nfull = (n4 / step) * step;
  long long i0 = (long long)blockIdx.x * (NT * 8) + tid;

  // --- self-sample: first 2 slabs (8192 elems/block) -> tspec ---------------
  {
    float s = 0.0f, ss = 0.0f; unsigned c = 0u;
    #pragma unroll
    for (int u = 0; u < 2; ++u) {
      long long i = i0 + u * NT;
      if (i < n4) {
        f32x4 v = x4[i];
        float e[4] = {v.x, v.y, v.z, v.w};
        #pragma unroll
        for (int k = 0; k < 4; ++k) {
          float ab = fabsf(e[k]);
          c += (ab != 0.0f) ? 1u : 0u;
          s += ab; ss += ab * ab;
        }
      }
    }
    #pragma unroll
    for (int off = 32; off > 0; off >>= 1) {
      s  += __shfl_down(s, off);
      ss += __shfl_down(ss, off);
      c  += __shfl_down(c, off);
    }
    if ((tid & 63) == 0) { s_s[tid >> 6] = s; s_ss[tid >> 6] = ss; s_c[tid >> 6] = (float)c; }
    __syncthreads();
    if (tid == 0) {
      float S = s_s[0] + s_s[1] + s_s[2] + s_s[3];
      float SS = s_ss[0] + s_ss[1] + s_ss[2] + s_ss[3];
      float C = s_c[0] + s_c[1] + s_c[2] + s_c[3];
      float nf = C > 1.0f ? C : 1.0f;
      float m = S / nf;
      float var = (SS - S * S / nf) / fmaxf(nf - 1.0f, 1.0f);
      var = fmaxf(var, 0.0f);
      s_tspec = 0.8f * (m + 3.0f * sqrtf(var));
    }
    __syncthreads();
  }
  float tspec = s_tspec;

  // --- main pass ------------------------------------------------------------
  Acc8 a0, a1; acc_init(a0); acc_init(a1);
  for (long long i = i0; i < nfull; i += step) {
    f32x4 v[8];
    #pragma unroll
    for (int u = 0; u < 8; ++u) v[u] = x4[i + u * NT];
    #pragma unroll
    for (int u = 0; u < 8; ++u) {
      Acc8& a = (u & 1) ? a1 : a0;
      proc1(v[u].x, tspec, a, &l_cnt, l_buf, st, bufA, capA);
      proc1(v[u].y, tspec, a, &l_cnt, l_buf, st, bufA, capA);
      proc1(v[u].z, tspec, a, &l_cnt, l_buf, st, bufA, capA);
      proc1(v[u].w, tspec, a, &l_cnt, l_buf, st, bufA, capA);
    }
  }
  for (long long i = nfull + gtid; i < n4; i += nthreads) {
    f32x4 v = x4[i];
    proc1(v.x, tspec, a0, &l_cnt, l_buf, st, bufA, capA);
    proc1(v.y, tspec, a0, &l_cnt, l_buf, st, bufA, capA);
    proc1(v.z, tspec, a0, &l_cnt, l_buf, st, bufA, capA);
    proc1(v.w, tspec, a0, &l_cnt, l_buf, st, bufA, capA);
  }
  for (long long i = (n4 << 2) + gtid; i < n; i += nthreads) {
    proc1(x[i], tspec, a0, &l_cnt, l_buf, st, bufA, capA);
  }

  // flush LDS-staged compaction, one global atomic per block
  __syncthreads();
  if (tid == 0) {
    l_m = l_cnt < LCAP ? l_cnt : LCAP;
    l_base = atomicAdd(&st->countA, l_m);
  }
  __syncthreads();
  for (unsigned i = tid; i < l_m; i += NT) {
    unsigned g = l_base + i;
    if (g < capA) bufA[g] = l_buf[i];
  }
  acc_merge(a0, a1);
  if (acc_block_reduce<4>(a0, s_part)) { part[blockIdx.x].a = a0; part[blockIdx.x].tspec = tspec; }
}

// ---------------------------------------------------------------------------
// K1R: reduce partials -> iter-0 stats + thr0; verify speculation; init the
// rest of State for downstream kernels.
// ---------------------------------------------------------------------------
__global__ void __launch_bounds__(1024) k1r_reduce(State* st, const AccP* __restrict__ part,
                                                   int np, unsigned capA) {
  __shared__ Acc8 s_part[16];
  __shared__ float s_tm[16];
  Acc8 a; acc_init(a);
  float tm = 0.0f;
  for (int j = threadIdx.x; j < np; j += 1024) {
    acc_merge(a, part[j].a);
    tm = fmaxf(tm, part[j].tspec);
  }
  // reduce tspec-max alongside
  #pragma unroll
  for (int off = 32; off > 0; off >>= 1) tm = fmaxf(tm, __shfl_down(tm, off));
  if ((threadIdx.x & 63) == 0) s_tm[threadIdx.x >> 6] = tm;
  if (acc_block_reduce<16>(a, s_part)) {
    #pragma unroll
    for (int w = 1; w < 16; ++w) tm = fmaxf(tm, s_tm[w]);
    st->sum0 = a.sum; st->sumsq0 = a.sumsq; st->n0 = a.cnt;
    st->maxabs0 = a.maxabs; st->minnz0 = a.minnz; st->maxnz0 = a.maxnz;
    float t = compute_thr(a.sum, a.sumsq, a.cnt);
    st->thr0f = t;
    st->special0 = (t > a.maxabs) ? 1 : 0;
    unsigned cA = st->countA;
    bool ok = (tm <= t) && (cA <= capA);
    st->fallback = ok ? 0 : 1;
    // bmin0/bmax0 seeded from spec-inliers iff speculation valid
    st->bmin0 = ok ? a.bmin : BIGF;
    st->bmax0 = ok ? a.bmax : -BIGF;
    // init everything downstream
    st->count1 = 0u; st->count2 = 0u;
    st->sum1 = 0.0; st->sumsq1 = 0.0; st->n1 = 0u;
    st->maxabs1 = a.maxabs;              // == maxabs0 whenever band-1 non-empty
    st->minnz1 = BIGF; st->maxnz1 = -BIGF;
    st->bmin1 = BIGF; st->bmax1 = -BIGF;
    st->sum2 = 0.0; st->sumsq2 = 0.0; st->n2 = 0u;
    st->maxabs2 = a.maxabs;
    st->minnz2 = BIGF; st->maxnz2 = -BIGF;
  }
}

// ---------------------------------------------------------------------------
// K2_FULL: correctness fallback (speculation failed). Early-exits otherwise.
// Old-k2 semantics: extend inlier min/max over all x, band-1 stats, compact
// {|x|>thr0} values into bufB. Atomic epilogue (rare path, perf irrelevant).
// ---------------------------------------------------------------------------
__global__ void __launch_bounds__(256) k2_full(const float* __restrict__ x, long long n, State* st,
                                               float* __restrict__ bufB, unsigned capB) {
  if (st->fallback == 0) return;
  __shared__ Acc8 s_part[4];
  __shared__ float l_buf[LCAP];
  __shared__ unsigned l_cnt, l_base, l_m;
  if (threadIdx.x == 0) l_cnt = 0u;
  __syncthreads();

  float thr0 = st->thr0f;
  bool special = st->special0 != 0;
  Acc8 a; acc_init(a);
  const f32x4* x4 = (const f32x4*)x;
  long long n4 = n >> 2;
  long long gtid = (long long)blockIdx.x * NT + threadIdx.x;
  long long nthreads = (long long)gridDim.x * NT;
  for (long long i = gtid; i < n4; i += nthreads) {
    f32x4 v = x4[i];
    float e[4] = {v.x, v.y, v.z, v.w};
    #pragma unroll
    for (int k = 0; k < 4; ++k) {
      float f = e[k];
      float ab = fabsf(f);
      bool out = ab > thr0;
      bool inl = special ? (f != 0.0f) : (!out);
      if (inl) { a.bmin = fminf(a.bmin, f); a.bmax = fmaxf(a.bmax, f); }
      if (out) {
        a.cnt++; a.sum += (double)ab; a.sumsq += (double)ab * (double)ab;
        a.minnz = fminf(a.minnz, f); a.maxnz = fmaxf(a.maxnz, f);
        unsigned p = atomicAdd(&l_cnt, 1u);
        if (p < LCAP) l_buf[p] = f;
        else { unsigned g = atomicAdd(&st->count1, 1u); if (g < capB) bufB[g] = f; }
      }
    }
  }
  for (long long i = (n4 << 2) + gtid; i < n; i += nthreads) {
    float f = x[i];
    float ab = fabsf(f);
    bool out = ab > thr0;
    bool inl = special ? (f != 0.0f) : (!out);
    if (inl) { a.bmin = fminf(a.bmin, f); a.bmax = fmaxf(a.bmax, f); }
    if (out) {
      a.cnt++; a.sum += (double)ab; a.sumsq += (double)ab * (double)ab;
      a.minnz = fminf(a.minnz, f); a.maxnz = fmaxf(a.maxnz, f);
      unsigned p = atomicAdd(&l_cnt, 1u);
      if (p < LCAP) l_buf[p] = f;
      else { unsigned g = atomicAdd(&st->count1, 1u); if (g < capB) bufB[g] = f; }
    }
  }
  __syncthreads();
  if (threadIdx.x == 0) {
    l_m = l_cnt < LCAP ? l_cnt : LCAP;
    l_base = atomicAdd(&st->count1, l_m);
  }
  __syncthreads();
  for (unsigned i = threadIdx.x; i < l_m; i += NT) {
    unsigned g = l_base + i;
    if (g < capB) bufB[g] = l_buf[i];
  }
  if (acc_block_reduce<4>(a, s_part)) {
    atomicMinF(&st->bmin0, a.bmin); atomicMaxF(&st->bmax0, a.bmax);
    atomicAdd(&st->sum1, a.sum); atomicAdd(&st->sumsq1, a.sumsq); atomicAdd(&st->n1, a.cnt);
    atomicMinF(&st->minnz1, a.minnz); atomicMaxF(&st->maxnz1, a.maxnz);
  }
}

// ---------------------------------------------------------------------------
// K2C: normal path — derive old-k2 outputs from the ~2.4M-record superset.
// Read bufA; recs with |x|<=thr0 extend bmin0/bmax0; recs with |x|>thr0 give
// band-1 stats and are compacted to bufB.
// ---------------------------------------------------------------------------
__global__ void __launch_bounds__(256) k2c_pass(State* st, const float* __restrict__ bufA, unsigned capA,
                                                float* __restrict__ bufB, unsigned capB) {
  if (st->fallback != 0) return;
  __shared__ Acc8 s_part[4];
  __shared__ float l_buf[LCAP];
  __shared__ unsigned l_cnt, l_base, l_m;
  if (threadIdx.x == 0) l_cnt = 0u;
  __syncthreads();

  unsigned cA = st->countA; if (cA > capA) cA = capA;
  float thr0 = st->thr0f;
  Acc8 a; acc_init(a);
  unsigned stride = gridDim.x * blockDim.x;
  unsigned cA4 = cA >> 2;
  const f32x4* bufA4 = (const f32x4*)bufA;
  for (unsigned j = blockIdx.x * blockDim.x + threadIdx.x; j < cA4; j += stride) {
    f32x4 v = bufA4[j];
    float e[4] = {v.x, v.y, v.z, v.w};
    #pragma unroll
    for (int k = 0; k < 4; ++k) {
      float f = e[k];
      float ab = fabsf(f);
      if (ab <= thr0) { a.bmin = fminf(a.bmin, f); a.bmax = fmaxf(a.bmax, f); }
      else {
        a.cnt++; a.sum += (double)ab; a.sumsq += (double)ab * (double)ab;
        a.minnz = fminf(a.minnz, f); a.maxnz = fmaxf(a.maxnz, f);
        unsigned p = atomicAdd(&l_cnt, 1u);
        if (p < LCAP) l_buf[p] = f;
        else { unsigned g = atomicAdd(&st->count1, 1u); if (g < capB) bufB[g] = f; }
      }
    }
  }
  for (unsigned j = (cA4 << 2) + blockIdx.x * blockDim.x + threadIdx.x; j < cA; j += stride) {
    float f = bufA[j];
    float ab = fabsf(f);
    if (ab <= thr0) { a.bmin = fminf(a.bmin, f); a.bmax = fmaxf(a.bmax, f); }
    else {
      a.cnt++; a.sum += (double)ab; a.sumsq += (double)ab * (double)ab;
      a.minnz = fminf(a.minnz, f); a.maxnz = fmaxf(a.maxnz, f);
      unsigned p = atomicAdd(&l_cnt, 1u);
      if (p < LCAP) l_buf[p] = f;
      else { unsigned g = atomicAdd(&st->count1, 1u); if (g < capB) bufB[g] = f; }
    }
  }
  __syncthreads();
  if (threadIdx.x == 0) {
    l_m = l_cnt < LCAP ? l_cnt : LCAP;
    l_base = atomicAdd(&st->count1, l_m);
  }
  __syncthreads();
  for (unsigned i = threadIdx.x; i < l_m; i += NT) {
    unsigned g = l_base + i;
    if (g < capB) bufB[g] = l_buf[i];
  }
  if (acc_block_reduce<4>(a, s_part)) {
    atomicMinF(&st->bmin0, a.bmin); atomicMaxF(&st->bmax0, a.bmax);
    atomicAdd(&st->sum1, a.sum); atomicAdd(&st->sumsq1, a.sumsq); atomicAdd(&st->n1, a.cnt);
    atomicMinF(&st->minnz1, a.minnz); atomicMaxF(&st->maxnz1, a.maxnz);
  }
}

// ---------------------------------------------------------------------------
// K3: over bufB (~614K): band-1 min/max, compact |x|>thr1 to buf2, band-2
// stats. thr1 computed from State sums (complete after k2c/k2_full).
// ---------------------------------------------------------------------------
__global__ void __launch_bounds__(256) k3_pass(State* st, const float* __restrict__ bufB, unsigned capB,
                                               float* __restrict__ buf2, unsigned cap2) {
  __shared__ Acc8 s_part[4];
  __shared__ float l_buf[LCAP];
  __shared__ unsigned l_cnt, l_base, l_m;
  if (threadIdx.x == 0) l_cnt = 0u;
  __syncthreads();

  unsigned c1 = st->count1; if (c1 > capB) c1 = capB;
  float thr1 = compute_thr(st->sum1, st->sumsq1, st->n1);

  Acc8 a; acc_init(a);
  unsigned stride = gridDim.x * blockDim.x;
  for (unsigned j = blockIdx.x * blockDim.x + threadIdx.x; j < c1; j += stride) {
    float f = bufB[j];
    float ab = fabsf(f);
    if (ab <= thr1) { a.bmin = fminf(a.bmin, f); a.bmax = fmaxf(a.bmax, f); }
    else {
      a.cnt++; a.sum += (double)ab; a.sumsq += (double)ab * (double)ab;
      a.minnz = fminf(a.minnz, f); a.maxnz = fmaxf(a.maxnz, f);
      unsigned p = atomicAdd(&l_cnt, 1u);
      if (p < LCAP) l_buf[p] = f;
      else { unsigned g = atomicAdd(&st->count2, 1u); if (g < cap2) buf2[g] = f; }
    }
  }
  __syncthreads();
  if (threadIdx.x == 0) {
    l_m = l_cnt < LCAP ? l_cnt : LCAP;
    l_base = atomicAdd(&st->count2, l_m);
  }
  __syncthreads();
  for (unsigned i = threadIdx.x; i < l_m; i += blockDim.x) {
    unsigned g = l_base + i;
    if (g < cap2) buf2[g] = l_buf[i];
  }
  if (acc_block_reduce<4>(a, s_part)) {
    atomicMinF(&st->bmin1, a.bmin); atomicMaxF(&st->bmax1, a.bmax);
    atomicAdd(&st->sum2, a.sum); atomicAdd(&st->sumsq2, a.sumsq); atomicAdd(&st->n2, a.cnt);
    atomicMinF(&st->minnz2, a.minnz); atomicMaxF(&st->maxnz2, a.maxnz);
  }
}

// ---------------------------------------------------------------------------
// K4: single block. Finalize groups 0,1; iterations 2..9 over buf2 (~7K);
// emit thr/delta/zp/valid tables.
// ---------------------------------------------------------------------------
__global__ void __launch_bounds__(1024) k4_finalize(State* st, const float* __restrict__ buf2, unsigned cap2) {
  __shared__ Acc8 s_part[16];
  __shared__ float sh_thr[10], sh_delta[10], sh_zp[10];
  __shared__ int sh_valid[10];
  __shared__ double sh_sum, sh_sumsq;
  __shared__ unsigned sh_n;
  __shared__ float sh_maxabs, sh_minnz, sh_maxnz;
  int tid = threadIdx.x;

  if (tid == 0) {
    float thr0 = compute_thr(st->sum0, st->sumsq0, st->n0);
    sh_thr[0] = thr0;
    finalize_group(thr0, st->maxabs0, st->n0, st->minnz0, st->maxnz0,
                   st->bmin0, st->bmax0, /*clampZero=*/false,
                   &sh_delta[0], &sh_zp[0], &sh_valid[0]);
    float thr1 = compute_thr(st->sum1, st->sumsq1, st->n1);
    sh_thr[1] = thr1;
    finalize_group(thr1, st->maxabs1, st->n1, st->minnz1, st->maxnz1,
                   st->bmin1, st->bmax1, /*clampZero=*/true,
                   &sh_delta[1], &sh_zp[1], &sh_valid[1]);
    sh_sum = st->sum2; sh_sumsq = st->sumsq2; sh_n = st->n2;
    sh_maxabs = st->maxabs2; sh_minnz = st->minnz2; sh_maxnz = st->maxnz2;
  }
  __syncthreads();
  unsigned c2 = st->count2; if (c2 > cap2) c2 = cap2;

  for (int i = 2; i < 10; ++i) {
    if (tid == 0) sh_thr[i] = compute_thr(sh_sum, sh_sumsq, sh_n);
    __syncthreads();
    float tp = sh_thr[i - 1], tc = sh_thr[i];
    Acc8 a; acc_init(a);
    for (unsigned j = tid; j < c2; j += 1024u) {
      float f = buf2[j];
      float ab = fabsf(f);
      if (ab > tp && ab <= tc) { a.bmin = fminf(a.bmin, f); a.bmax = fmaxf(a.bmax, f); }
      if (ab > tc) {
        a.cnt++; a.sum += (double)ab; a.sumsq += (double)ab * (double)ab;
        a.maxabs = fmaxf(a.maxabs, ab);
        a.minnz = fminf(a.minnz, f); a.maxnz = fmaxf(a.maxnz, f);
      }
    }
    if (acc_block_reduce<16>(a, s_part)) {
      finalize_group(tc, sh_maxabs, sh_n, sh_minnz, sh_maxnz, a.bmin, a.bmax,
                     /*clampZero=*/true, &sh_delta[i], &sh_zp[i], &sh_valid[i]);
      if (sh_n > 0u) {  // done-propagation: keep zeros once dead
        sh_sum = a.sum; sh_sumsq = a.sumsq; sh_n = a.cnt;
        sh_maxabs = a.maxabs; sh_minnz = a.minnz; sh_maxnz = a.maxnz;
      }
    }
    __syncthreads();
  }
  if (tid < 10) {
    st->thr[tid] = sh_thr[tid]; st->delta[tid] = sh_delta[tid];
    st->zp[tid] = sh_zp[tid];   st->valid[tid] = sh_valid[tid];
  }
}

// ---------------------------------------------------------------------------
// K5: dequant everything. Band-0 fast path; wave-uniform escape to the full
// chain only when some lane holds an outlier (~47% of wave-slots). Numerics
// per element identical to the accepted chain in both paths.
// ---------------------------------------------------------------------------
__device__ inline float dq0(float v, float d0, float z0) {
  float q = rintf(v / d0) + z0;
  q = fminf(fmaxf(q, 0.0f), 255.0f);
  return (q - z0) * d0;
}
__device__ inline float dq1(float v, const float* thr, const float* dl, const float* zp, const int* vld) {
  float ab = fabsf(v);
  float d = dl[0], z = zp[0];
  #pragma unroll
  for (int i = 1; i < 10; ++i) {
    bool band = (vld[i] != 0) && (ab > thr[i - 1]) && (ab <= thr[i]);
    d = band ? dl[i] : d;
    z = band ? zp[i] : z;
  }
  float q = rintf(v / d) + z;
  q = fminf(fmaxf(q, 0.0f), 255.0f);
  return (q - z) * d;
}
__device__ inline float dq(float v, float t0, float d0, float z0,
                           const float* thr, const float* dl, const float* zp, const int* vld) {
  if (__any(fabsf(v) > t0)) return dq1(v, thr, dl, zp, vld);
  return dq0(v, d0, z0);
}

__global__ void __launch_bounds__(256) k5_dequant(const float* __restrict__ x, float* __restrict__ out,
                                                  long long n, const State* __restrict__ st) {
  float thr[10], dl[10], zp[10]; int vld[10];
  #pragma unroll
  for (int i = 0; i < 10; ++i) {
    thr[i] = st->thr[i]; dl[i] = st->delta[i]; zp[i] = st->zp[i]; vld[i] = st->valid[i];
  }
  float d0 = dl[0], z0 = zp[0], t0 = thr[0];
  const f32x4* x4 = (const f32x4*)x;
  f32x4* o4 = (f32x4*)out;
  long long n4 = n >> 2;
  long long gtid = (long long)blockIdx.x * NT + threadIdx.x;
  long long nthreads = (long long)gridDim.x * NT;
  long long step = nthreads * 8;
  long long nfull = (n4 / step) * step;
  for (long long i = (long long)blockIdx.x * (NT * 8) + threadIdx.x; i < nfull; i += step) {
    f32x4 v[8];
    #pragma unroll
    for (int u = 0; u < 8; ++u) v[u] = __builtin_nontemporal_load(&x4[i + u * NT]);
    #pragma unroll
    for (int u = 0; u < 8; ++u) {
      f32x4 o;
      o.x = dq(v[u].x, t0, d0, z0, thr, dl, zp, vld);
      o.y = dq(v[u].y, t0, d0, z0, thr, dl, zp, vld);
      o.z = dq(v[u].z, t0, d0, z0, thr, dl, zp, vld);
      o.w = dq(v[u].w, t0, d0, z0, thr, dl, zp, vld);
      __builtin_nontemporal_store(o, &o4[i + u * NT]);
    }
  }
  for (long long i = nfull + gtid; i < n4; i += nthreads) {
    f32x4 v = x4[i];
    f32x4 o;
    o.x = dq(v.x, t0, d0, z0, thr, dl, zp, vld);
    o.y = dq(v.y, t0, d0, z0, thr, dl, zp, vld);
    o.z = dq(v.z, t0, d0, z0, thr, dl, zp, vld);
    o.w = dq(v.w, t0, d0, z0, thr, dl, zp, vld);
    o4[i] = o;
  }
  for (long long i = (n4 << 2) + gtid; i < n; i += nthreads) {
    out[i] = dq(x[i], t0, d0, z0, thr, dl, zp, vld);
  }
}

// ---------------------------------------------------------------------------
extern "C" void kernel_launch(void* const* d_in, const int* in_sizes, int n_in,
                              void* d_out, int out_size, void* d_ws, size_t ws_size,
                              hipStream_t stream) {
  const float* x = (const float*)d_in[0];
  float* out = (float*)d_out;
  long long n = (long long)in_sizes[0];

  // ws carve: State | partials | buf2 | bufB | bufA
  char* p = (char*)d_ws;
  State* st = (State*)p;            p += 4096;
  AccP* part = (AccP*)p;            p += (size_t)NB * sizeof(AccP);
  size_t used = (size_t)(p - (char*)d_ws);
  used = (used + 255) & ~(size_t)255;
  size_t avail = ws_size > used ? ws_size - used : 0;
  size_t b2_sz = (avail / 16) & ~(size_t)255;
  size_t bB_sz = (avail / 4) & ~(size_t)255;
  size_t bA_sz = avail - b2_sz - bB_sz;
  float* buf2 = (float*)((char*)d_ws + used);
  float* bufB = (float*)((char*)buf2 + b2_sz);
  float* bufA = (float*)((char*)bufB + bB_sz);
  unsigned cap2 = (unsigned)(b2_sz / 4);
  unsigned capB = (unsigned)(bB_sz / 4);
  unsigned capA = (unsigned)(bA_sz / 4);

  hipLaunchKernelGGL(k0_init,     dim3(1),   dim3(64),   0, stream, st);
  hipLaunchKernelGGL(k1_stats,    dim3(NB),  dim3(NT),   0, stream, x, n, part, bufA, capA, st);
  hipLaunchKernelGGL(k1r_reduce,  dim3(1),   dim3(1024), 0, stream, st, (const AccP*)part, NB, capA);
  hipLaunchKernelGGL(k2_full,     dim3(NB),  dim3(NT),   0, stream, x, n, st, bufB, capB);
  hipLaunchKernelGGL(k2c_pass,    dim3(512), dim3(NT),   0, stream, st, (const float*)bufA, capA, bufB, capB);
  hipLaunchKernelGGL(k3_pass,     dim3(256), dim3(NT),   0, stream, st, (const float*)bufB, capB, buf2, cap2);
  hipLaunchKernelGGL(k4_finalize, dim3(1),   dim3(1024), 0, stream, st, (const float*)buf2, cap2);
  hipLaunchKernelGGL(k5_dequant,  dim3(NB),  dim3(NT),   0, stream, x, out, n, st);
}